// Round 2
// baseline (155.061 us; speedup 1.0000x reference)
//
#include <hip/hip_runtime.h>
#include <stdint.h>

// SPN forward, single-wave-per-plane design.
// [B*C=256 planes] x [H=256 rows] x [W=256 cols], fp32.
// One 64-lane wave per plane; lane l owns rows 4l..4l+3 with h-state in
// registers. Vertical neighbor exchange: in-lane registers + 2 shuffles/col.
// NO barriers anywhere. Global->LDS staging via global_load_lds with a
// counted-vmcnt FIFO pipeline (double-buffered 8-column stages). Output is
// transposed through LDS and stored as coalesced float4 rows.

#define HD 256
#define WD 256
#define SW 8                  // stage width (columns)
#define NS (WD / SW)          // 32 stages
#define WIN_B 1040            // 32 rows * 32 B + 16 B pad (bank-quad stagger)
#define ARR_B (8 * WIN_B)     // 8 windows per array per stage = 8320 B
#define STAGE_B (4 * ARR_B)   // x,g1,g2,g3 = 33280 B
#define OUT_STRIDE 260        // out tile [SW][260] dwords (pad 4 -> 2-way max)
#define OUT_OFF (2 * STAGE_B)

#define F4E(v, e) ((e) == 0 ? (v).x : (e) == 1 ? (v).y : (e) == 2 ? (v).z : (v).w)

__global__ __launch_bounds__(64, 1) void spn_fwd(
    const float* __restrict__ x, const float* __restrict__ G1,
    const float* __restrict__ G2, const float* __restrict__ G3,
    float* __restrict__ out)
{
  // 74880 B used; padded >80 KiB so exactly 1 block/CU.
  __shared__ __align__(16) char lds[83200];

  const int l = threadIdx.x;
  const size_t pbase = (size_t)blockIdx.x * (HD * WD);
  const float* gp0 = x  + pbase;
  const float* gp1 = G1 + pbase;
  const float* gp2 = G2 + pbase;
  const float* gp3 = G3 + pbase;
  float* op = out + pbase;

  // staging: lane covers row (32k + (l>>1)), cols scol..scol+3 of the stage
  const int srow = l >> 1;
  const int scol = (l & 1) * 4;

  auto issue_stage = [&](int t, int buf) {
    char* sb = lds + (buf ? STAGE_B : 0);
    const int j0 = t * SW;
    const float* ga_[4] = {gp0, gp1, gp2, gp3};
#pragma unroll
    for (int A = 0; A < 4; ++A) {
      const float* base = ga_[A] + ((size_t)srow * WD + j0 + scol);
#pragma unroll
      for (int k = 0; k < 8; ++k) {
        __builtin_amdgcn_global_load_lds(
            (const __attribute__((address_space(1))) void*)(base + (size_t)k * 32 * WD),
            (__attribute__((address_space(3))) void*)(sb + A * ARR_B + k * WIN_B),
            16, 0, 0);
      }
    }
  };

  // consumer LDS base: window g = l>>3, in-window row block (l&7)*4
  const int lb = (l >> 3) * WIN_B + (l & 7) * 128;
  const float mU = (l > 0) ? 1.f : 0.f;    // row 0 has no up-neighbor
  const float mD = (l < 63) ? 1.f : 0.f;   // row 255 has no down-neighbor
  float* outldsF = (float*)(lds + OUT_OFF);

  float h[4] = {0.f, 0.f, 0.f, 0.f};

  issue_stage(0, 0);
  issue_stage(1, 1);

#pragma unroll 1
  for (int t = 0; t < NS; ++t) {
    // FIFO vmcnt: ops issued after L_t = {stores_{t-2}(8), L_{t+1}(32), stores_{t-1}(8)}
    if (t == 0)           asm volatile("s_waitcnt vmcnt(32)" ::: "memory");
    else if (t == 1)      asm volatile("s_waitcnt vmcnt(40)" ::: "memory");
    else if (t == NS - 1) asm volatile("s_waitcnt vmcnt(16)" ::: "memory");
    else                  asm volatile("s_waitcnt vmcnt(48)" ::: "memory");

    const char* sb = lds + ((t & 1) ? STAGE_B : 0);
    const float cOkF = (t == 0) ? 0.f : 1.f;   // column 0: all gates zeroed

#pragma unroll
    for (int cc = 0; cc < 2; ++cc) {
      float4 vx[4], va[4], vb[4], vc[4];
#pragma unroll
      for (int r = 0; r < 4; ++r) {
        const int off = lb + r * 32 + cc * 16;
        vx[r] = *(const float4*)(sb + 0 * ARR_B + off);
        va[r] = *(const float4*)(sb + 1 * ARR_B + off);
        vb[r] = *(const float4*)(sb + 2 * ARR_B + off);
        vc[r] = *(const float4*)(sb + 3 * ARR_B + off);
      }
#pragma unroll
      for (int e = 0; e < 4; ++e) {
        const float shU = __shfl_up(h[3], 1);    // h[4l-1] from lane l-1
        const float shD = __shfl_down(h[0], 1);  // h[4l+4] from lane l+1
        float hn[4];
#pragma unroll
        for (int r = 0; r < 4; ++r) {
          float aa = F4E(va[r], e), bb = F4E(vb[r], e);
          float cg = F4E(vc[r], e), xx = F4E(vx[r], e);
          float s = fabsf(aa) + fabsf(bb) + fabsf(cg);
          float inv = (s >= 1.f) ? __builtin_amdgcn_rcpf(s) : 1.f;
          float ga = aa * inv, gb = bb * inv, gc = cg * inv;
          if (cc == 0 && e == 0) { ga *= cOkF; gb *= cOkF; gc *= cOkF; }
          if (r == 0) ga *= mU;
          if (r == 3) gc *= mD;
          float up = (r == 0) ? shU : h[r - 1];
          float dn = (r == 3) ? shD : h[r + 1];
          hn[r] = (1.f - ga - gb - gc) * xx + ga * up + gb * h[r] + gc * dn;
        }
#pragma unroll
        for (int r = 0; r < 4; ++r) h[r] = hn[r];
        // transposed out tile: [colInStage][260 rows], conflict-free b128
        *(float4*)(outldsF + (cc * 4 + e) * OUT_STRIDE + 4 * l) =
            make_float4(hn[0], hn[1], hn[2], hn[3]);
      }
    }

    // all ds_reads of this staging buffer are consumed; safe to refill it
    asm volatile("s_waitcnt lgkmcnt(0)" ::: "memory");
    if (t + 2 < NS) issue_stage(t + 2, t & 1);

    // coalesced store: lane reads its row-chunk from the transposed tile
    const int j0 = t * SW;
#pragma unroll
    for (int k = 0; k < 8; ++k) {
      const int row = k * 32 + srow;
      float4 o;
      o.x = outldsF[(scol + 0) * OUT_STRIDE + row];
      o.y = outldsF[(scol + 1) * OUT_STRIDE + row];
      o.z = outldsF[(scol + 2) * OUT_STRIDE + row];
      o.w = outldsF[(scol + 3) * OUT_STRIDE + row];
      *(float4*)(op + (size_t)row * WD + j0 + scol) = o;
    }
  }
}

extern "C" void kernel_launch(void* const* d_in, const int* in_sizes, int n_in,
                              void* d_out, int out_size, void* d_ws, size_t ws_size,
                              hipStream_t stream) {
  const float* x  = (const float*)d_in[0];
  const float* g1 = (const float*)d_in[1];
  const float* g2 = (const float*)d_in[2];
  const float* g3 = (const float*)d_in[3];
  float* outp = (float*)d_out;
  const int planes = out_size / (HD * WD);   // B*C = 256
  spn_fwd<<<planes, 64, 0, stream>>>(x, g1, g2, g3, outp);
}